// Round 24
// baseline (194.589 us; speedup 1.0000x reference)
//
#include <hip/hip_runtime.h>
#include <stdint.h>

typedef float  fx4  __attribute__((ext_vector_type(4)));
typedef short  bfx8 __attribute__((ext_vector_type(8)));
typedef short  bfx4 __attribute__((ext_vector_type(4)));
typedef unsigned short ux4 __attribute__((ext_vector_type(4)));
typedef unsigned int   ux2 __attribute__((ext_vector_type(2)));

#define AS1 __attribute__((address_space(1)))
#define AS3 __attribute__((address_space(3)))

#define GLOAD_LDS16(g, l) __builtin_amdgcn_global_load_lds( \
    (const AS1 unsigned int*)(g), (AS3 unsigned int*)(l), 16, 0, 0)

__device__ __forceinline__ unsigned int cvtpk(float lo, float hi) {
  unsigned int r;
  asm("v_cvt_pk_bf16_f32 %0, %1, %2" : "=v"(r) : "v"(lo), "v"(hi));
  return r;
}

// value-level pack: 4 fp32 -> 4 bf16 (short-based, same TBAA class as bfx8 reads)
__device__ __forceinline__ bfx4 pack4(fx4 v) {
  union { unsigned int u[2]; bfx4 s; } x;
  x.u[0] = cvtpk(v[0], v[1]);
  x.u[1] = cvtpk(v[2], v[3]);
  return x.s;
}

// grouped XCD swizzle: XCD k = o&7 owns tm in [8k, 8k+8); its 8 co-resident
// tn-blocks share each A panel in k's private L2 (bijective map).
__device__ __forceinline__ void xcd_group_swizzle(int o, int& tm, int& tn) {
  const int k = o & 7, idx = o >> 3;
  tn = idx & 7;
  tm = k * 8 + (idx >> 3);
}

#define BM 128
#define BN 128
#define BK 32

// ---------------- fused QKV projection GEMM, fully reg-staged ------------
// 3 segments x 512 blocks, grouped XCD swizzle (R19), both operands
// reg-staged one iteration deep (R20/R22). R24: B reads fp32 weights
// DIRECTLY (same fp32->pack4 template as A) -- cvt4 kernel deleted.
// Barrier drains only lgkm; all global-load latency has a full-iter window.
__global__ __launch_bounds__(256, 3) void qkv_gemm(
    const float* __restrict__ Xq, const float* __restrict__ Xk,
    const float* __restrict__ Xv,
    const float* __restrict__ Wq, const float* __restrict__ Wk,
    const float* __restrict__ Wv,
    const float* __restrict__ bq, const float* __restrict__ bk,
    const float* __restrict__ bv,
    unsigned short* __restrict__ Qh, unsigned short* __restrict__ Kh,
    unsigned short* __restrict__ VT)
{
  __shared__ unsigned short sA[2][BM * BK];
  __shared__ unsigned short sB[2][BN * BK];
  const int tid = threadIdx.x, lane = tid & 63, w = tid >> 6;
  const int g = lane >> 4, c = lane & 15;
  const int seg = blockIdx.x >> 9;           // 0=Q 1=K 2=V
  int tm, tn;
  xcd_group_swizzle(blockIdx.x & 511, tm, tn);
  const int wr = w >> 1, wc = w & 1;

  const float* A    = seg == 0 ? Xq : seg == 1 ? Xk : Xv;
  const float* Bw   = seg == 0 ? Wq : seg == 1 ? Wk : Wv;
  const float* bias = seg == 0 ? bq : seg == 1 ? bk : bv;

  fx4 acc[4][4];
#pragma unroll
  for (int i = 0; i < 4; i++)
#pragma unroll
    for (int j = 0; j < 4; j++) { fx4 z = {0.f,0.f,0.f,0.f}; acc[i][j] = z; }

  // each tile = 128x32 fp32 = 1024 fx4 chunks; thread t owns chunks t+256i.
  fx4 areg[4], breg[4];
  auto loadA = [&](int kt_) {
#pragma unroll
    for (int i = 0; i < 4; i++) {
      int ch = i * 256 + tid;
      int row_ = ch >> 3, c4 = ch & 7;
      areg[i] = *reinterpret_cast<const fx4*>(
          A + (size_t)(tm * BM + row_) * 1024 + kt_ * BK + c4 * 4);
    }
  };
  auto loadB = [&](int kt_) {
#pragma unroll
    for (int i = 0; i < 4; i++) {
      int ch = i * 256 + tid;
      int row_ = ch >> 3, c4 = ch & 7;
      breg[i] = *reinterpret_cast<const fx4*>(
          Bw + (size_t)(tn * BN + row_) * 1024 + kt_ * BK + c4 * 4);
    }
  };
  auto writeA = [&](int buf_) {
#pragma unroll
    for (int i = 0; i < 4; i++) {
      int ch = i * 256 + tid;
      int row_ = ch >> 3, c4 = ch & 7;
      *reinterpret_cast<bfx4*>(sA[buf_] + row_ * BK + c4 * 4) = pack4(areg[i]);
    }
  };
  auto writeB = [&](int buf_) {
#pragma unroll
    for (int i = 0; i < 4; i++) {
      int ch = i * 256 + tid;
      int row_ = ch >> 3, c4 = ch & 7;
      *reinterpret_cast<bfx4*>(sB[buf_] + row_ * BK + c4 * 4) = pack4(breg[i]);
    }
  };

  // prologue: tile 0 staged to LDS; tile 1 held in registers
  loadA(0); loadB(0);
  writeA(0); writeB(0);
  loadA(1); loadB(1);       // tile 1 in flight across the barrier
  __syncthreads();          // tile 0 ready (lgkm drain)

  int buf = 0;
  for (int kt = 0; kt < 32; ++kt) {
    // top: stage tile kt+1 into buf^1 (regs loaded one full iter earlier)
    if (kt + 1 < 32) {
      writeA(buf ^ 1);
      writeB(buf ^ 1);
      if (kt + 2 < 32) { loadA(kt + 2); loadB(kt + 2); }
    }

    bfx8 af[4], bfr[4];
#pragma unroll
    for (int i = 0; i < 4; i++)
      af[i] = *reinterpret_cast<const bfx8*>(sA[buf] + (wr * 64 + i * 16 + c) * BK + g * 8);
#pragma unroll
    for (int j = 0; j < 4; j++)
      bfr[j] = *reinterpret_cast<const bfx8*>(sB[buf] + (wc * 64 + j * 16 + c) * BK + g * 8);
#pragma unroll
    for (int i = 0; i < 4; i++)
#pragma unroll
      for (int j = 0; j < 4; j++)
        acc[i][j] = __builtin_amdgcn_mfma_f32_16x16x32_bf16(af[i], bfr[j], acc[i][j], 0, 0, 0);

    __syncthreads();   // drains only lgkm (ds_writes) -- no vm drain
    buf ^= 1;
  }

  if (seg < 2) {
    // [B,H,L,Dh] bf16; Q pre-scaled by 1/8 * log2(e)
    unsigned short* Cout = seg ? Kh : Qh;
    const float scale = seg ? 1.0f : 0.18033688011112042f;
#pragma unroll
    for (int j = 0; j < 4; j++) {
      const int col = tn * BN + wc * 64 + j * 16 + c;
      const float bb = bias[col];
      const int h = col >> 6, d = col & 63;
#pragma unroll
      for (int i = 0; i < 4; i++) {
        const int row0 = tm * BM + wr * 64 + i * 16 + g * 4;
#pragma unroll
        for (int r = 0; r < 4; r++) {
          const int m = row0 + r;
          const int b = m >> 11, lq = m & 2047;
          float vv = (acc[i][j][r] + bb) * scale;
          union { unsigned int u; float f; } xx; xx.f = vv;
          Cout[((size_t)((b * 16 + h) * 2048 + lq)) * 64 + d] =
              (unsigned short)((xx.u + 0x7fffu + ((xx.u >> 16) & 1u)) >> 16);
        }
      }
    }
  } else {
    // V transposed [B,H,Dh,L]; 4 contiguous lq -> one 8B store
#pragma unroll
    for (int j = 0; j < 4; j++) {
      const int col = tn * BN + wc * 64 + j * 16 + c;
      const float bb = bias[col];
      const int h = col >> 6, d = col & 63;
#pragma unroll
      for (int i = 0; i < 4; i++) {
        const int row0 = tm * BM + wr * 64 + i * 16 + g * 4;
        const int b = row0 >> 11, lq0 = row0 & 2047;
        ux2 u;
        u[0] = cvtpk(acc[i][j][0] + bb, acc[i][j][1] + bb);
        u[1] = cvtpk(acc[i][j][2] + bb, acc[i][j][3] + bb);
        *reinterpret_cast<ux2*>(VT + ((size_t)((b * 16 + h) * 64 + d)) * 2048 + lq0) = u;
      }
    }
  }
}

// ---------------- output projection GEMM, fully reg-staged ---------------
// A = bf16 AO (reg-staged bfx8), B = fp32 Wo (reg-staged fp32->pack4).
__global__ __launch_bounds__(256, 3) void gemm_out(
    const unsigned short* __restrict__ AO, const float* __restrict__ Wo,
    const float* __restrict__ bo, float* __restrict__ out)
{
  __shared__ unsigned short sA[2][BM * BK];
  __shared__ unsigned short sB[2][BN * BK];
  const int tid = threadIdx.x, lane = tid & 63, w = tid >> 6;
  const int g = lane >> 4, c = lane & 15;
  int tm, tn;
  xcd_group_swizzle(blockIdx.x, tm, tn);
  const int wr = w >> 1, wc = w & 1;

  fx4 acc[4][4];
#pragma unroll
  for (int i = 0; i < 4; i++)
#pragma unroll
    for (int j = 0; j < 4; j++) { fx4 z = {0.f,0.f,0.f,0.f}; acc[i][j] = z; }

  bfx8 areg[2];
  fx4  breg[4];
  auto loadA = [&](int kt_) {
#pragma unroll
    for (int i_ = 0; i_ < 2; i_++) {
      int ch_ = (w * 2 + i_) * 64 + lane;
      int row_ = ch_ >> 2, cc_ = ch_ & 3;
      areg[i_] = *reinterpret_cast<const bfx8*>(
          AO + (size_t)(tm * BM + row_) * 1024 + kt_ * BK + cc_ * 8);
    }
  };
  auto loadB = [&](int kt_) {
#pragma unroll
    for (int i = 0; i < 4; i++) {
      int ch = i * 256 + tid;
      int row_ = ch >> 3, c4 = ch & 7;
      breg[i] = *reinterpret_cast<const fx4*>(
          Wo + (size_t)(tn * BN + row_) * 1024 + kt_ * BK + c4 * 4);
    }
  };
  auto writeA = [&](int buf_) {
#pragma unroll
    for (int i_ = 0; i_ < 2; i_++) {
      int ch_ = (w * 2 + i_) * 64 + lane;
      *reinterpret_cast<bfx8*>(sA[buf_] + ch_ * 8) = areg[i_];
    }
  };
  auto writeB = [&](int buf_) {
#pragma unroll
    for (int i = 0; i < 4; i++) {
      int ch = i * 256 + tid;
      int row_ = ch >> 3, c4 = ch & 7;
      *reinterpret_cast<bfx4*>(sB[buf_] + row_ * BK + c4 * 4) = pack4(breg[i]);
    }
  };

  loadA(0); loadB(0);
  writeA(0); writeB(0);
  loadA(1); loadB(1);
  __syncthreads();

  int buf = 0;
  for (int kt = 0; kt < 32; ++kt) {
    if (kt + 1 < 32) {
      writeA(buf ^ 1);
      writeB(buf ^ 1);
      if (kt + 2 < 32) { loadA(kt + 2); loadB(kt + 2); }
    }

    bfx8 af[4], bfr[4];
#pragma unroll
    for (int i = 0; i < 4; i++)
      af[i] = *reinterpret_cast<const bfx8*>(sA[buf] + (wr * 64 + i * 16 + c) * BK + g * 8);
#pragma unroll
    for (int j = 0; j < 4; j++)
      bfr[j] = *reinterpret_cast<const bfx8*>(sB[buf] + (wc * 64 + j * 16 + c) * BK + g * 8);
#pragma unroll
    for (int i = 0; i < 4; i++)
#pragma unroll
      for (int j = 0; j < 4; j++)
        acc[i][j] = __builtin_amdgcn_mfma_f32_16x16x32_bf16(af[i], bfr[j], acc[i][j], 0, 0, 0);

    __syncthreads();
    buf ^= 1;
  }

#pragma unroll
  for (int j = 0; j < 4; j++) {
    const int col = tn * BN + wc * 64 + j * 16 + c;
    const float bb = bo[col];
#pragma unroll
    for (int i = 0; i < 4; i++) {
      const int row0 = tm * BM + wr * 64 + i * 16 + g * 4;
#pragma unroll
      for (int r = 0; r < 4; r++)
        out[(size_t)(row0 + r) * 1024 + col] = acc[i][j][r] + bb;
    }
  }
}

// ---------------- flash attention, max-free softmax (R17 body, verbatim) --
__global__ __launch_bounds__(256, 4) void attn_fwd(
    const unsigned short* __restrict__ Qh,   // [B*H][2048][64] pre-scaled
    const unsigned short* __restrict__ Kh,   // [B*H][2048][64]
    const unsigned short* __restrict__ VT,   // [B*H][64][2048]
    unsigned short* __restrict__ AO)         // [B][2048][1024] bf16
{
  __shared__ unsigned short sK[2][64 * 64];
  __shared__ unsigned short sV[2][64 * 64];
  __shared__ unsigned short sP[4][16 * 64];
  const int tid  = threadIdx.x;
  const int lane = tid & 63, w = tid >> 6;
  const int g = lane >> 4, c = lane & 15;
  const int orig = blockIdx.x;
  const int swz  = (orig & 7) * 128 + (orig >> 3);
  const int qt = swz & 15, bh = swz >> 4;

  const size_t hbase = (size_t)bh * 2048 * 64;

  bfx8 qf[2][2];
  const size_t qrow0 = (size_t)bh * 2048 + qt * 128 + w * 32;
#pragma unroll
  for (int q_ = 0; q_ < 2; q_++)
#pragma unroll
    for (int kk = 0; kk < 2; kk++)
      qf[q_][kk] = *reinterpret_cast<const bfx8*>(Qh + (qrow0 + q_ * 16 + c) * 64 + kk * 32 + g * 8);

  fx4 O[2][4];
  float lr[2];
#pragma unroll
  for (int q_ = 0; q_ < 2; q_++) {
#pragma unroll
    for (int dd = 0; dd < 4; dd++) { fx4 z = {0.f,0.f,0.f,0.f}; O[q_][dd] = z; }
    lr[q_] = 0.f;
  }

  auto stage = [&](int buf, int t) {
#pragma unroll
    for (int i = 0; i < 2; i++) {
      int ch  = (w * 2 + i) * 64 + lane;
      int row = ch >> 3;
      int c16 = (ch & 7) ^ (row & 7);
      GLOAD_LDS16(Kh + hbase + (size_t)(t * 64 + row) * 64 + c16 * 8,
                  &sK[buf][(w * 2 + i) * 512]);
      GLOAD_LDS16(VT + hbase + (size_t)row * 2048 + t * 64 + c16 * 8,
                  &sV[buf][(w * 2 + i) * 512]);
    }
  };

  stage(0, 0);
  __syncthreads();

  const int NT = 2048 / 64;
  int cur = 0;
  for (int t = 0; t < NT; ++t) {
    if (t + 1 < NT) stage(cur ^ 1, t + 1);

    const unsigned short* sKc = sK[cur];
    const unsigned short* sVc = sV[cur];
    unsigned short* sPw = &sP[w][0];

    // ---- S^T = mfma32(K, Q) ----
    fx4 S[2][4];
#pragma unroll
    for (int q_ = 0; q_ < 2; q_++)
#pragma unroll
      for (int f = 0; f < 4; f++) { fx4 z = {0.f,0.f,0.f,0.f}; S[q_][f] = z; }
    __builtin_amdgcn_s_setprio(1);
#pragma unroll
    for (int f = 0; f < 4; f++) {
      const int row = f * 16 + c;
#pragma unroll
      for (int kk = 0; kk < 2; kk++) {
        bfx8 kf = *reinterpret_cast<const bfx8*>(sKc + row * 64 + (((4 * kk + g) ^ (row & 7)) * 8));
        S[0][f] = __builtin_amdgcn_mfma_f32_16x16x32_bf16(kf, qf[0][kk], S[0][f], 0, 0, 0);
        S[1][f] = __builtin_amdgcn_mfma_f32_16x16x32_bf16(kf, qf[1][kk], S[1][f], 0, 0, 0);
      }
    }
    __builtin_amdgcn_s_setprio(0);

    // ---- max-free softmax accumulation, lane-local (q=c) ----
    bfx8 pB[2][2];
#pragma unroll
    for (int q_ = 0; q_ < 2; q_++) {
      float rs = 0.f;
#pragma unroll
      for (int f = 0; f < 4; f++) {
        float p0 = __builtin_amdgcn_exp2f(S[q_][f][0]);
        float p1 = __builtin_amdgcn_exp2f(S[q_][f][1]);
        float p2 = __builtin_amdgcn_exp2f(S[q_][f][2]);
        float p3 = __builtin_amdgcn_exp2f(S[q_][f][3]);
        rs += (p0 + p1) + (p2 + p3);
        ux2 pkt; pkt[0] = cvtpk(p0, p1); pkt[1] = cvtpk(p2, p3);
        *reinterpret_cast<ux2*>(sPw + c * 64 + (((2 * f + (g >> 1)) ^ (c & 7)) * 8) + (g & 1) * 4) = pkt;
      }
      rs += __shfl_xor(rs, 16);
      rs += __shfl_xor(rs, 32);
      lr[q_] += rs;
#pragma unroll
      for (int kk = 0; kk < 2; kk++)
        pB[q_][kk] = *reinterpret_cast<const bfx8*>(sPw + c * 64 + (((4 * kk + g) ^ (c & 7)) * 8));
    }

    // ---- O^T += mfma32(V^T-as-A, P^T-as-B) ----
    __builtin_amdgcn_s_setprio(1);
#pragma unroll
    for (int kk = 0; kk < 2; ++kk) {
#pragma unroll
      for (int dd = 0; dd < 4; ++dd) {
        const int row = dd * 16 + c;
        bfx8 vf = *reinterpret_cast<const bfx8*>(sVc + row * 64 + (((4 * kk + g) ^ (row & 7)) * 8));
        O[0][dd] = __builtin_amdgcn_mfma_f32_16x16x32_bf16(vf, pB[0][kk], O[0][dd], 0, 0, 0);
        O[1][dd] = __builtin_amdgcn_mfma_f32_16x16x32_bf16(vf, pB[1][kk], O[1][dd], 0, 0, 0);
      }
    }
    __builtin_amdgcn_s_setprio(0);

    __syncthreads();
    cur ^= 1;
  }

  // ---- epilogue ----
  const int b = bh >> 4, h = bh & 15;
#pragma unroll
  for (int q_ = 0; q_ < 2; q_++) {
    const float inv = 1.0f / lr[q_];
    const size_t row = (size_t)qt * 128 + w * 32 + q_ * 16 + c;
#pragma unroll
    for (int dd = 0; dd < 4; dd++) {
      float v0 = O[q_][dd][0] * inv, v1 = O[q_][dd][1] * inv;
      float v2 = O[q_][dd][2] * inv, v3 = O[q_][dd][3] * inv;
      ux2 u; u[0] = cvtpk(v0, v1); u[1] = cvtpk(v2, v3);
      *reinterpret_cast<ux2*>(AO + ((size_t)b * 2048 + row) * 1024 + h * 64 + dd * 16 + g * 4) = u;
    }
  }
}

// ---------------- launch ----------------
extern "C" void kernel_launch(void* const* d_in, const int* in_sizes, int n_in,
                              void* d_out, int out_size, void* d_ws, size_t ws_size,
                              hipStream_t stream) {
  (void)in_sizes; (void)n_in; (void)out_size; (void)ws_size;
  const float* q  = (const float*)d_in[0];
  const float* k  = (const float*)d_in[1];
  const float* v  = (const float*)d_in[2];
  const float* Wq = (const float*)d_in[3];
  const float* bq = (const float*)d_in[4];
  const float* Wk = (const float*)d_in[5];
  const float* bk = (const float*)d_in[6];
  const float* Wv = (const float*)d_in[7];
  const float* bv = (const float*)d_in[8];
  const float* Wo = (const float*)d_in[9];
  const float* bo = (const float*)d_in[10];
  float* out = (float*)d_out;

  // NO ALIASING: every buffer has a private region. (64MB total)
  unsigned char* ws = (unsigned char*)d_ws;
  const size_t MB = 1u << 20;
  unsigned short* Qh = (unsigned short*)(ws +  0 * MB);  // 16MB
  unsigned short* Kh = (unsigned short*)(ws + 16 * MB);  // 16MB
  unsigned short* VT = (unsigned short*)(ws + 32 * MB);  // 16MB
  unsigned short* AO = (unsigned short*)(ws + 48 * MB);  // 16MB

  qkv_gemm<<<1536, 256, 0, stream>>>(q, k, v, Wq, Wk, Wv, bq, bk, bv, Qh, Kh, VT);

  attn_fwd<<<1024, 256, 0, stream>>>(Qh, Kh, VT, AO);

  gemm_out<<<512, 256, 0, stream>>>(AO, Wo, bo, out);
}

// Round 25
// 190.999 us; speedup vs baseline: 1.0188x; 1.0188x over previous
//
#include <hip/hip_runtime.h>
#include <stdint.h>

typedef float  fx4  __attribute__((ext_vector_type(4)));
typedef short  bfx8 __attribute__((ext_vector_type(8)));
typedef short  bfx4 __attribute__((ext_vector_type(4)));
typedef unsigned short ux4 __attribute__((ext_vector_type(4)));
typedef unsigned int   ux2 __attribute__((ext_vector_type(2)));

#define AS1 __attribute__((address_space(1)))
#define AS3 __attribute__((address_space(3)))

#define GLOAD_LDS16(g, l) __builtin_amdgcn_global_load_lds( \
    (const AS1 unsigned int*)(g), (AS3 unsigned int*)(l), 16, 0, 0)

__device__ __forceinline__ unsigned short f2bf(float f) {
  union { float f; unsigned int u; } x; x.f = f;
  return (unsigned short)((x.u + 0x7fffu + ((x.u >> 16) & 1u)) >> 16);
}

__device__ __forceinline__ unsigned int cvtpk(float lo, float hi) {
  unsigned int r;
  asm("v_cvt_pk_bf16_f32 %0, %1, %2" : "=v"(r) : "v"(lo), "v"(hi));
  return r;
}

// value-level pack: 4 fp32 -> 4 bf16 (short-based, same TBAA class as bfx8 reads)
__device__ __forceinline__ bfx4 pack4(fx4 v) {
  union { unsigned int u[2]; bfx4 s; } x;
  x.u[0] = cvtpk(v[0], v[1]);
  x.u[1] = cvtpk(v[2], v[3]);
  return x.s;
}

// grouped XCD swizzle: XCD k = o&7 owns tm in [8k, 8k+8); its 8 co-resident
// tn-blocks share each A panel in k's private L2 (bijective map).
__device__ __forceinline__ void xcd_group_swizzle(int o, int& tm, int& tn) {
  const int k = o & 7, idx = o >> 3;
  tn = idx & 7;
  tm = k * 8 + (idx >> 3);
}

// ---------------- fp32 -> bf16 convert: weights only (4 x 1MB) -----------
__global__ __launch_bounds__(256) void cvt4_f32_bf16(
    const float* __restrict__ a, const float* __restrict__ b,
    const float* __restrict__ cc, const float* __restrict__ d,
    unsigned short* __restrict__ oa, unsigned short* __restrict__ ob,
    unsigned short* __restrict__ oc, unsigned short* __restrict__ od) {
  const int y = blockIdx.y;
  const float* in = (y == 0) ? a : (y == 1) ? b : (y == 2) ? cc : d;
  unsigned short* out = (y == 0) ? oa : (y == 1) ? ob : (y == 2) ? oc : od;
  int i = blockIdx.x * 256 + threadIdx.x;
  fx4 v = reinterpret_cast<const fx4*>(in)[i];
  ux4 o;
  o[0] = f2bf(v[0]); o[1] = f2bf(v[1]); o[2] = f2bf(v[2]); o[3] = f2bf(v[3]);
  reinterpret_cast<ux4*>(out)[i] = o;
}

#define BM 128
#define BN 128
#define BK 32

// ---------------- fused QKV projection GEMM, fully reg-staged (R22) ------
__global__ __launch_bounds__(256, 3) void qkv_gemm(
    const float* __restrict__ Xq, const float* __restrict__ Xk,
    const float* __restrict__ Xv,
    const unsigned short* __restrict__ Wqb, const unsigned short* __restrict__ Wkb,
    const unsigned short* __restrict__ Wvb,
    const float* __restrict__ bq, const float* __restrict__ bk,
    const float* __restrict__ bv,
    unsigned short* __restrict__ Qh, unsigned short* __restrict__ Kh,
    unsigned short* __restrict__ VT)
{
  __shared__ unsigned short sA[2][BM * BK];
  __shared__ unsigned short sB[2][BN * BK];
  const int tid = threadIdx.x, lane = tid & 63, w = tid >> 6;
  const int g = lane >> 4, c = lane & 15;
  const int seg = blockIdx.x >> 9;           // 0=Q 1=K 2=V
  int tm, tn;
  xcd_group_swizzle(blockIdx.x & 511, tm, tn);
  const int wr = w >> 1, wc = w & 1;

  const float* A           = seg == 0 ? Xq  : seg == 1 ? Xk  : Xv;
  const unsigned short* Bw = seg == 0 ? Wqb : seg == 1 ? Wkb : Wvb;
  const float* bias        = seg == 0 ? bq  : seg == 1 ? bk  : bv;

  fx4 acc[4][4];
#pragma unroll
  for (int i = 0; i < 4; i++)
#pragma unroll
    for (int j = 0; j < 4; j++) { fx4 z = {0.f,0.f,0.f,0.f}; acc[i][j] = z; }

  // A tile = 128x32 fp32 = 1024 fx4 chunks; thread t owns chunks t+256i.
  fx4 areg[4];
  auto loadA = [&](int kt_) {
#pragma unroll
    for (int i = 0; i < 4; i++) {
      int ch = i * 256 + tid;
      int row_ = ch >> 3, c4 = ch & 7;
      areg[i] = *reinterpret_cast<const fx4*>(
          A + (size_t)(tm * BM + row_) * 1024 + kt_ * BK + c4 * 4);
    }
  };
  auto writeA = [&](int buf_) {
#pragma unroll
    for (int i = 0; i < 4; i++) {
      int ch = i * 256 + tid;
      int row_ = ch >> 3, c4 = ch & 7;
      *reinterpret_cast<bfx4*>(sA[buf_] + row_ * BK + c4 * 4) = pack4(areg[i]);
    }
  };

  // B tile = 128x32 bf16 = 512 chunks of 8 shorts; thread t owns 2 chunks.
  bfx8 breg[2];
  auto loadB = [&](int kt_) {
#pragma unroll
    for (int i_ = 0; i_ < 2; i_++) {
      int ch_ = (w * 2 + i_) * 64 + lane;
      int row_ = ch_ >> 2, cc_ = ch_ & 3;
      breg[i_] = *reinterpret_cast<const bfx8*>(
          Bw + (size_t)(tn * BN + row_) * 1024 + kt_ * BK + cc_ * 8);
    }
  };
  auto writeB = [&](int buf_) {
#pragma unroll
    for (int i_ = 0; i_ < 2; i_++) {
      int ch_ = (w * 2 + i_) * 64 + lane;
      *reinterpret_cast<bfx8*>(sB[buf_] + ch_ * 8) = breg[i_];
    }
  };

  // prologue: tile 0 staged to LDS; tile 1 held in registers
  loadA(0); loadB(0);
  writeA(0); writeB(0);
  loadA(1); loadB(1);       // tile 1 in flight across the barrier
  __syncthreads();          // tile 0 ready (lgkm drain)

  int buf = 0;
  for (int kt = 0; kt < 32; ++kt) {
    // top: stage tile kt+1 into buf^1 (regs loaded one full iter earlier)
    if (kt + 1 < 32) {
      writeA(buf ^ 1);
      writeB(buf ^ 1);
      if (kt + 2 < 32) { loadA(kt + 2); loadB(kt + 2); }
    }

    bfx8 af[4], bfr[4];
#pragma unroll
    for (int i = 0; i < 4; i++)
      af[i] = *reinterpret_cast<const bfx8*>(sA[buf] + (wr * 64 + i * 16 + c) * BK + g * 8);
#pragma unroll
    for (int j = 0; j < 4; j++)
      bfr[j] = *reinterpret_cast<const bfx8*>(sB[buf] + (wc * 64 + j * 16 + c) * BK + g * 8);
#pragma unroll
    for (int i = 0; i < 4; i++)
#pragma unroll
      for (int j = 0; j < 4; j++)
        acc[i][j] = __builtin_amdgcn_mfma_f32_16x16x32_bf16(af[i], bfr[j], acc[i][j], 0, 0, 0);

    __syncthreads();   // drains only lgkm (ds_writes) -- no vm drain
    buf ^= 1;
  }

  if (seg < 2) {
    // [B,H,L,Dh] bf16; Q pre-scaled by 1/8 * log2(e)
    unsigned short* Cout = seg ? Kh : Qh;
    const float scale = seg ? 1.0f : 0.18033688011112042f;
#pragma unroll
    for (int j = 0; j < 4; j++) {
      const int col = tn * BN + wc * 64 + j * 16 + c;
      const float bb = bias[col];
      const int h = col >> 6, d = col & 63;
#pragma unroll
      for (int i = 0; i < 4; i++) {
        const int row0 = tm * BM + wr * 64 + i * 16 + g * 4;
#pragma unroll
        for (int r = 0; r < 4; r++) {
          const int m = row0 + r;
          const int b = m >> 11, lq = m & 2047;
          Cout[((size_t)((b * 16 + h) * 2048 + lq)) * 64 + d] =
              f2bf((acc[i][j][r] + bb) * scale);
        }
      }
    }
  } else {
    // V transposed [B,H,Dh,L]; 4 contiguous lq -> one 8B store
#pragma unroll
    for (int j = 0; j < 4; j++) {
      const int col = tn * BN + wc * 64 + j * 16 + c;
      const float bb = bias[col];
      const int h = col >> 6, d = col & 63;
#pragma unroll
      for (int i = 0; i < 4; i++) {
        const int row0 = tm * BM + wr * 64 + i * 16 + g * 4;
        const int b = row0 >> 11, lq0 = row0 & 2047;
        ux2 u;
        u[0] = cvtpk(acc[i][j][0] + bb, acc[i][j][1] + bb);
        u[1] = cvtpk(acc[i][j][2] + bb, acc[i][j][3] + bb);
        *reinterpret_cast<ux2*>(VT + ((size_t)((b * 16 + h) * 64 + d)) * 2048 + lq0) = u;
      }
    }
  }
}

// ---------------- output projection GEMM, fully reg-staged (R23) ---------
__global__ __launch_bounds__(256, 3) void gemm_out(
    const unsigned short* __restrict__ AO, const unsigned short* __restrict__ Wob,
    const float* __restrict__ bo, float* __restrict__ out)
{
  __shared__ unsigned short sA[2][BM * BK];
  __shared__ unsigned short sB[2][BN * BK];
  const int tid = threadIdx.x, lane = tid & 63, w = tid >> 6;
  const int g = lane >> 4, c = lane & 15;
  int tm, tn;
  xcd_group_swizzle(blockIdx.x, tm, tn);
  const int wr = w >> 1, wc = w & 1;

  fx4 acc[4][4];
#pragma unroll
  for (int i = 0; i < 4; i++)
#pragma unroll
    for (int j = 0; j < 4; j++) { fx4 z = {0.f,0.f,0.f,0.f}; acc[i][j] = z; }

  bfx8 areg[2], breg[2];
  auto loadAB = [&](int kt_) {
#pragma unroll
    for (int i_ = 0; i_ < 2; i_++) {
      int ch_ = (w * 2 + i_) * 64 + lane;
      int row_ = ch_ >> 2, cc_ = ch_ & 3;
      areg[i_] = *reinterpret_cast<const bfx8*>(
          AO  + (size_t)(tm * BM + row_) * 1024 + kt_ * BK + cc_ * 8);
      breg[i_] = *reinterpret_cast<const bfx8*>(
          Wob + (size_t)(tn * BN + row_) * 1024 + kt_ * BK + cc_ * 8);
    }
  };
  auto writeAB = [&](int buf_) {
#pragma unroll
    for (int i_ = 0; i_ < 2; i_++) {
      int ch_ = (w * 2 + i_) * 64 + lane;
      *reinterpret_cast<bfx8*>(sA[buf_] + ch_ * 8) = areg[i_];
      *reinterpret_cast<bfx8*>(sB[buf_] + ch_ * 8) = breg[i_];
    }
  };

  loadAB(0);
  writeAB(0);
  loadAB(1);
  __syncthreads();

  int buf = 0;
  for (int kt = 0; kt < 32; ++kt) {
    if (kt + 1 < 32) {
      writeAB(buf ^ 1);
      if (kt + 2 < 32) loadAB(kt + 2);
    }

    bfx8 af[4], bfr[4];
#pragma unroll
    for (int i = 0; i < 4; i++)
      af[i] = *reinterpret_cast<const bfx8*>(sA[buf] + (wr * 64 + i * 16 + c) * BK + g * 8);
#pragma unroll
    for (int j = 0; j < 4; j++)
      bfr[j] = *reinterpret_cast<const bfx8*>(sB[buf] + (wc * 64 + j * 16 + c) * BK + g * 8);
#pragma unroll
    for (int i = 0; i < 4; i++)
#pragma unroll
      for (int j = 0; j < 4; j++)
        acc[i][j] = __builtin_amdgcn_mfma_f32_16x16x32_bf16(af[i], bfr[j], acc[i][j], 0, 0, 0);

    __syncthreads();
    buf ^= 1;
  }

#pragma unroll
  for (int j = 0; j < 4; j++) {
    const int col = tn * BN + wc * 64 + j * 16 + c;
    const float bb = bo[col];
#pragma unroll
    for (int i = 0; i < 4; i++) {
      const int row0 = tm * BM + wr * 64 + i * 16 + g * 4;
#pragma unroll
      for (int r = 0; r < 4; r++)
        out[(size_t)(row0 + r) * 1024 + col] = acc[i][j][r] + bb;
    }
  }
}

// ---------------- flash attention, max-free softmax (R17 body, verbatim) --
__global__ __launch_bounds__(256, 4) void attn_fwd(
    const unsigned short* __restrict__ Qh,   // [B*H][2048][64] pre-scaled
    const unsigned short* __restrict__ Kh,   // [B*H][2048][64]
    const unsigned short* __restrict__ VT,   // [B*H][64][2048]
    unsigned short* __restrict__ AO)         // [B][2048][1024] bf16
{
  __shared__ unsigned short sK[2][64 * 64];
  __shared__ unsigned short sV[2][64 * 64];
  __shared__ unsigned short sP[4][16 * 64];
  const int tid  = threadIdx.x;
  const int lane = tid & 63, w = tid >> 6;
  const int g = lane >> 4, c = lane & 15;
  const int orig = blockIdx.x;
  const int swz  = (orig & 7) * 128 + (orig >> 3);
  const int qt = swz & 15, bh = swz >> 4;

  const size_t hbase = (size_t)bh * 2048 * 64;

  bfx8 qf[2][2];
  const size_t qrow0 = (size_t)bh * 2048 + qt * 128 + w * 32;
#pragma unroll
  for (int q_ = 0; q_ < 2; q_++)
#pragma unroll
    for (int kk = 0; kk < 2; kk++)
      qf[q_][kk] = *reinterpret_cast<const bfx8*>(Qh + (qrow0 + q_ * 16 + c) * 64 + kk * 32 + g * 8);

  fx4 O[2][4];
  float lr[2];
#pragma unroll
  for (int q_ = 0; q_ < 2; q_++) {
#pragma unroll
    for (int dd = 0; dd < 4; dd++) { fx4 z = {0.f,0.f,0.f,0.f}; O[q_][dd] = z; }
    lr[q_] = 0.f;
  }

  auto stage = [&](int buf, int t) {
#pragma unroll
    for (int i = 0; i < 2; i++) {
      int ch  = (w * 2 + i) * 64 + lane;
      int row = ch >> 3;
      int c16 = (ch & 7) ^ (row & 7);
      GLOAD_LDS16(Kh + hbase + (size_t)(t * 64 + row) * 64 + c16 * 8,
                  &sK[buf][(w * 2 + i) * 512]);
      GLOAD_LDS16(VT + hbase + (size_t)row * 2048 + t * 64 + c16 * 8,
                  &sV[buf][(w * 2 + i) * 512]);
    }
  };

  stage(0, 0);
  __syncthreads();

  const int NT = 2048 / 64;
  int cur = 0;
  for (int t = 0; t < NT; ++t) {
    if (t + 1 < NT) stage(cur ^ 1, t + 1);

    const unsigned short* sKc = sK[cur];
    const unsigned short* sVc = sV[cur];
    unsigned short* sPw = &sP[w][0];

    // ---- S^T = mfma32(K, Q) ----
    fx4 S[2][4];
#pragma unroll
    for (int q_ = 0; q_ < 2; q_++)
#pragma unroll
      for (int f = 0; f < 4; f++) { fx4 z = {0.f,0.f,0.f,0.f}; S[q_][f] = z; }
    __builtin_amdgcn_s_setprio(1);
#pragma unroll
    for (int f = 0; f < 4; f++) {
      const int row = f * 16 + c;
#pragma unroll
      for (int kk = 0; kk < 2; kk++) {
        bfx8 kf = *reinterpret_cast<const bfx8*>(sKc + row * 64 + (((4 * kk + g) ^ (row & 7)) * 8));
        S[0][f] = __builtin_amdgcn_mfma_f32_16x16x32_bf16(kf, qf[0][kk], S[0][f], 0, 0, 0);
        S[1][f] = __builtin_amdgcn_mfma_f32_16x16x32_bf16(kf, qf[1][kk], S[1][f], 0, 0, 0);
      }
    }
    __builtin_amdgcn_s_setprio(0);

    // ---- max-free softmax accumulation, lane-local (q=c) ----
    bfx8 pB[2][2];
#pragma unroll
    for (int q_ = 0; q_ < 2; q_++) {
      float rs = 0.f;
#pragma unroll
      for (int f = 0; f < 4; f++) {
        float p0 = __builtin_amdgcn_exp2f(S[q_][f][0]);
        float p1 = __builtin_amdgcn_exp2f(S[q_][f][1]);
        float p2 = __builtin_amdgcn_exp2f(S[q_][f][2]);
        float p3 = __builtin_amdgcn_exp2f(S[q_][f][3]);
        rs += (p0 + p1) + (p2 + p3);
        ux2 pkt; pkt[0] = cvtpk(p0, p1); pkt[1] = cvtpk(p2, p3);
        *reinterpret_cast<ux2*>(sPw + c * 64 + (((2 * f + (g >> 1)) ^ (c & 7)) * 8) + (g & 1) * 4) = pkt;
      }
      rs += __shfl_xor(rs, 16);
      rs += __shfl_xor(rs, 32);
      lr[q_] += rs;
#pragma unroll
      for (int kk = 0; kk < 2; kk++)
        pB[q_][kk] = *reinterpret_cast<const bfx8*>(sPw + c * 64 + (((4 * kk + g) ^ (c & 7)) * 8));
    }

    // ---- O^T += mfma32(V^T-as-A, P^T-as-B) ----
    __builtin_amdgcn_s_setprio(1);
#pragma unroll
    for (int kk = 0; kk < 2; ++kk) {
#pragma unroll
      for (int dd = 0; dd < 4; ++dd) {
        const int row = dd * 16 + c;
        bfx8 vf = *reinterpret_cast<const bfx8*>(sVc + row * 64 + (((4 * kk + g) ^ (row & 7)) * 8));
        O[0][dd] = __builtin_amdgcn_mfma_f32_16x16x32_bf16(vf, pB[0][kk], O[0][dd], 0, 0, 0);
        O[1][dd] = __builtin_amdgcn_mfma_f32_16x16x32_bf16(vf, pB[1][kk], O[1][dd], 0, 0, 0);
      }
    }
    __builtin_amdgcn_s_setprio(0);

    __syncthreads();
    cur ^= 1;
  }

  // ---- epilogue ----
  const int b = bh >> 4, h = bh & 15;
#pragma unroll
  for (int q_ = 0; q_ < 2; q_++) {
    const float inv = 1.0f / lr[q_];
    const size_t row = (size_t)qt * 128 + w * 32 + q_ * 16 + c;
#pragma unroll
    for (int dd = 0; dd < 4; dd++) {
      float v0 = O[q_][dd][0] * inv, v1 = O[q_][dd][1] * inv;
      float v2 = O[q_][dd][2] * inv, v3 = O[q_][dd][3] * inv;
      ux2 u; u[0] = cvtpk(v0, v1); u[1] = cvtpk(v2, v3);
      *reinterpret_cast<ux2*>(AO + ((size_t)b * 2048 + row) * 1024 + h * 64 + dd * 16 + g * 4) = u;
    }
  }
}

// ---------------- launch ----------------
extern "C" void kernel_launch(void* const* d_in, const int* in_sizes, int n_in,
                              void* d_out, int out_size, void* d_ws, size_t ws_size,
                              hipStream_t stream) {
  (void)in_sizes; (void)n_in; (void)out_size; (void)ws_size;
  const float* q  = (const float*)d_in[0];
  const float* k  = (const float*)d_in[1];
  const float* v  = (const float*)d_in[2];
  const float* Wq = (const float*)d_in[3];
  const float* bq = (const float*)d_in[4];
  const float* Wk = (const float*)d_in[5];
  const float* bk = (const float*)d_in[6];
  const float* Wv = (const float*)d_in[7];
  const float* bv = (const float*)d_in[8];
  const float* Wo = (const float*)d_in[9];
  const float* bo = (const float*)d_in[10];
  float* out = (float*)d_out;

  // NO ALIASING: every buffer has a private region.
  unsigned char* ws = (unsigned char*)d_ws;
  const size_t MB = 1u << 20;
  unsigned short* Qh  = (unsigned short*)(ws +  0 * MB);  // 16MB
  unsigned short* Kh  = (unsigned short*)(ws + 16 * MB);  // 16MB
  unsigned short* VT  = (unsigned short*)(ws + 32 * MB);  // 16MB
  unsigned short* AO  = (unsigned short*)(ws + 48 * MB);  // 16MB
  unsigned short* Wqb = (unsigned short*)(ws + 64 * MB);  // 2MB each
  unsigned short* Wkb = (unsigned short*)(ws + 66 * MB);
  unsigned short* Wvb = (unsigned short*)(ws + 68 * MB);
  unsigned short* Wob = (unsigned short*)(ws + 70 * MB);  // total 72MB

  cvt4_f32_bf16<<<dim3(1024, 4), 256, 0, stream>>>(Wq, Wk, Wv, Wo, Wqb, Wkb, Wvb, Wob);

  qkv_gemm<<<1536, 256, 0, stream>>>(q, k, v, Wqb, Wkb, Wvb, bq, bk, bv, Qh, Kh, VT);

  attn_fwd<<<1024, 256, 0, stream>>>(Qh, Kh, VT, AO);

  gemm_out<<<512, 256, 0, stream>>>(AO, Wob, bo, out);
}